// Round 15
// baseline (215.234 us; speedup 1.0000x reference)
//
#include <hip/hip_runtime.h>
#include <stdint.h>

// ---- problem constants ----
#define Tn   2048
#define Cn   2048
#define Hn   32
#define KVHn 8
#define Dn   64
#define MR   4096   // B*T
#define NQKV 3072   // 2048 q | 512 k | 512 v
#define KD   2048

typedef __attribute__((ext_vector_type(4))) float fx4;
typedef __attribute__((ext_vector_type(8))) short frag8;

#define MFMA(a,b,c) __builtin_amdgcn_mfma_f32_16x16x32_bf16((a),(b),(c),0,0,0)

struct __align__(16) U16x8 { unsigned short s[8]; };

__device__ __forceinline__ unsigned short f2bf(float x){
  union { float f; unsigned u; } v; v.f = x;
  return (unsigned short)((v.u + 0x7FFFu + ((v.u >> 16) & 1u)) >> 16);
}
__device__ __forceinline__ float bf2f(unsigned short h){
  union { unsigned u; float f; } v; v.u = ((unsigned)h) << 16; return v.f;
}
// exp2 via compiler-known intrinsic (hazard-safe)
__device__ __forceinline__ float sexp2(float x){
#if __has_builtin(__builtin_amdgcn_exp2f)
  return __builtin_amdgcn_exp2f(x);
#else
  return exp2f(x);
#endif
}
__device__ __forceinline__ unsigned cvtpk(float a, float b){
  unsigned r; asm("v_cvt_pk_bf16_f32 %0, %1, %2" : "=v"(r) : "v"(a), "v"(b)); return r;
}

typedef const __attribute__((address_space(1))) void cas1_void;
typedef __attribute__((address_space(3))) void as3_void;
__device__ __forceinline__ void gld16(const void* g, void* l){
  __builtin_amdgcn_global_load_lds((cas1_void*)g, (as3_void*)l, 16, 0, 0);
}

// ---- merged prep: [0,2048) x->bf16 cvt | [2048,3584) transW qkv | [3584,4608) transW o | [4608,4864) rope table ----
__global__ __launch_bounds__(256) void k_prep(const float* __restrict__ x, unsigned short* __restrict__ xb,
                                              const float* __restrict__ Wq, const float* __restrict__ Wk,
                                              const float* __restrict__ Wv, unsigned short* __restrict__ wqkvt,
                                              const float* __restrict__ Wo, unsigned short* __restrict__ wot,
                                              float2* __restrict__ cs){
  __shared__ float tile[64][65];
  int blk = blockIdx.x, t = threadIdx.x;
  if (blk < 2048) {
    size_t blockbase = (size_t)blk * 4096;
    #pragma unroll
    for (int j = 0; j < 4; ++j) {
      size_t i = blockbase + j * 1024 + t * 4;
      float4 v = *(const float4*)(x + i);
      ushort4 o; o.x = f2bf(v.x); o.y = f2bf(v.y); o.z = f2bf(v.z); o.w = f2bf(v.w);
      *(ushort4*)(xb + i) = o;
    }
    return;
  }
  if (blk >= 4608) {
    int i = (blk - 4608) * 256 + t;
    int tp = i >> 5, d = i & 31;
    float inv = powf(10000.0f, -(float)d * (1.0f/32.0f));
    float fr = (float)tp * inv;
    cs[i] = make_float2(cosf(fr), sinf(fr));
    return;
  }
  const float* src; int col0, ld, n0, k0; unsigned short* outp;
  if (blk < 3584) {
    int bx = blk - 2048; n0 = (bx % 48) * 64; k0 = (bx / 48) * 64; outp = wqkvt;
    if (n0 < 2048)      { src = Wq; col0 = n0;        ld = 2048; }
    else if (n0 < 2560) { src = Wk; col0 = n0 - 2048; ld = 512;  }
    else                { src = Wv; col0 = n0 - 2560; ld = 512;  }
  } else {
    int bx = blk - 3584; n0 = (bx % 32) * 64; k0 = (bx / 32) * 64; outp = wot;
    src = Wo; col0 = n0; ld = 2048;
  }
  int r = t >> 2, cc = (t & 3) << 4;
  const float* p = src + (size_t)(k0 + r) * ld + col0 + cc;
  #pragma unroll
  for (int j = 0; j < 16; j += 4) {
    float4 v = *(const float4*)(p + j);
    tile[r][cc + j + 0] = v.x; tile[r][cc + j + 1] = v.y;
    tile[r][cc + j + 2] = v.z; tile[r][cc + j + 3] = v.w;
  }
  __syncthreads();
  int n = t >> 2, kc = (t & 3) << 4;
  unsigned short* q = outp + (size_t)(n0 + n) * 2048 + k0 + kc;
  U16x8 o0, o1;
  #pragma unroll
  for (int j = 0; j < 8; ++j) o0.s[j] = f2bf(tile[kc + j][n]);
  #pragma unroll
  for (int j = 0; j < 8; ++j) o1.s[j] = f2bf(tile[kc + 8 + j][n]);
  *(U16x8*)(q) = o0;
  *(U16x8*)(q + 8) = o1;
}

// ---- m97-style 128x128 GEMM
//      MODE 0: plain f32 C store (GEMM2)
//      MODE 2: fused epilogue (GEMM1): q/k blocks -> in-register rope -> bf16 qkv;
//              v blocks -> in-LDS transpose -> quad-interleaved vtb (k_vt folded in) ----
template<int MODE>
__global__ __launch_bounds__(256) void k_gemm(const unsigned short* __restrict__ A,
                                              const unsigned short* __restrict__ Bt,
                                              void* __restrict__ Cp,
                                              int M, int N, int K,
                                              const float2* __restrict__ cs,
                                              unsigned short* __restrict__ vtb){
  __shared__ unsigned short POOL[2 * 128 * 64];   // As | Bs ; reused by v-epilogue
  unsigned short* As = POOL;
  unsigned short* Bs = POOL + 128 * 64;
  int tid = threadIdx.x;
  int m0 = blockIdx.y * 128, n0 = blockIdx.x * 128;
  int w = tid >> 6, ln = tid & 63, lr = ln & 15, lg = ln >> 4;
  int wm = (w >> 1) * 64, wn = (w & 1) * 64;
  fx4 acc[4][4];
  #pragma unroll
  for (int i = 0; i < 4; ++i)
    #pragma unroll
    for (int j = 0; j < 4; ++j) acc[i][j] = (fx4){0.f,0.f,0.f,0.f};
  int steps = K >> 6;
  for (int kt = 0; kt < steps; ++kt) {
    int kb = kt << 6;
    #pragma unroll
    for (int it = 0; it < 4; ++it) {
      int nch = it * 256 + tid;
      int r = nch >> 3, c = (nch & 7) ^ (r & 7);   // source-side swizzle, linear LDS dest
      gld16(A  + (size_t)(m0 + r) * K + kb + c * 8, (char*)As + nch * 16);
      gld16(Bt + (size_t)(n0 + r) * K + kb + c * 8, (char*)Bs + nch * 16);
    }
    __syncthreads();
    frag8 aF[4][2], bF[4][2];
    #pragma unroll
    for (int i = 0; i < 4; ++i) {
      int ra = wm + i * 16 + lr;
      int rb = wn + i * 16 + lr;
      #pragma unroll
      for (int kk = 0; kk < 2; ++kk) {
        aF[i][kk] = *(const frag8*)((const char*)As + ra * 128 + (((lg + 4*kk) ^ (ra & 7)) << 4));
        bF[i][kk] = *(const frag8*)((const char*)Bs + rb * 128 + (((lg + 4*kk) ^ (rb & 7)) << 4));
      }
    }
    #pragma unroll
    for (int kk = 0; kk < 2; ++kk)
      #pragma unroll
      for (int i = 0; i < 4; ++i)
        #pragma unroll
        for (int j = 0; j < 4; ++j)
          acc[i][j] = MFMA(aF[i][kk], bF[j][kk], acc[i][j]);
    __syncthreads();
  }
  if (MODE == 0) {
    #pragma unroll
    for (int i = 0; i < 4; ++i) {
      int row = m0 + wm + i * 16 + lg * 4;
      #pragma unroll
      for (int j = 0; j < 4; ++j) {
        int col = n0 + wn + j * 16 + lr;
        #pragma unroll
        for (int rr = 0; rr < 4; ++rr)
          ((float*)Cp)[(size_t)(row + rr) * N + col] = acc[i][j][rr];
      }
    }
  } else {
    int nb = n0 + wn;                       // 64-aligned -> one head per window
    unsigned short* outp = (unsigned short*)Cp;
    if (nb < 2560) {
      // ---- q/k block: rope in-register (fp32 accum), bf16 store to qkv ----
      float sc = (n0 < 2048) ? 0.180336880f : 1.0f;   // q: 0.125*log2(e)
      #pragma unroll
      for (int i = 0; i < 4; ++i) {
        int rowb = m0 + wm + i * 16 + lg * 4;
        #pragma unroll
        for (int jp = 0; jp < 2; ++jp) {
          int dA = jp * 16 + lr;            // d mod 32
          #pragma unroll
          for (int rr = 0; rr < 4; ++rr) {
            int row = rowb + rr;
            float2 cv = cs[((row & (Tn-1)) << 5) + dA];
            float a = acc[i][jp][rr], b = acc[i][jp + 2][rr];
            outp[(size_t)row * N + nb + dA]      = f2bf((a * cv.x - b * cv.y) * sc);
            outp[(size_t)row * N + nb + dA + 32] = f2bf((b * cv.x + a * cv.y) * sc);
          }
        }
      }
    } else {
      // ---- v block: in-LDS transpose (per-wave 8KB of POOL, free after K-loop's
      //      final barrier) -> quad-interleaved vtb write with 16B stores.
      //      LDS layout [d=64][t=64] bf16, row stride 128B, 16B-unit XOR swizzle
      //      ^((d&7)<<4). Same-wave write->read (compiler orders via lgkmcnt). ----
      char* tlb = (char*)(POOL + w * 4096);
      #pragma unroll
      for (int i = 0; i < 4; ++i) {
        int tcol2 = (i * 16 + lg * 4) * 2;           // byte offset along t
        #pragma unroll
        for (int j = 0; j < 4; ++j) {
          int d = j * 16 + lr;
          unsigned lo = cvtpk(acc[i][j][0], acc[i][j][1]);   // t64 +0,+1
          unsigned hi = cvtpk(acc[i][j][2], acc[i][j][3]);   // t64 +2,+3
          *(uint2*)(tlb + d * 128 + (tcol2 ^ ((d & 7) << 4))) = make_uint2(lo, hi);
        }
      }
      int kvh = (nb - 2560) >> 6;
      int bb = (m0 + wm) >> 11;
      int t0 = (m0 + wm) & (Tn - 1);
      const char* myrow = tlb + ln * 128;            // lane owns d = ln
      int sx = (ln & 7) << 4;
      unsigned short* vq = vtb + ((size_t)(bb * 8 + kvh) * 64 + ln) * Tn + t0;
      #pragma unroll
      for (int c = 0; c < 8; ++c) {
        // chunk c element e: t64 = 32*(c>>2) + 16*(e>>2) + 4*(c&3) + (e&3)
        int e0 = 64 * (c >> 2) + 8 * (c & 3);        // byte offset of run e=0..3
        uint2 lo = *(const uint2*)(myrow + (e0 ^ sx));
        uint2 hi = *(const uint2*)(myrow + ((e0 + 32) ^ sx));   // run e=4..7 (+16 elems)
        *(uint4*)(vq + c * 8) = make_uint4(lo.x, lo.y, hi.x, hi.y);
      }
    }
  }
}

// ---- flash attention (R12-proven): QBLK=256 (8 waves x 32 q-rows), KVBLK=64,
//      swapped QK^T, fixed softmax origin, P in registers, per-lane l,
//      quad-buffered LDS (barrier per 2 tiles), cross-tile PV pipeline with
//      double vf state, setprio on MFMA. ----
__global__ __launch_bounds__(512) void k_attn(const unsigned short* __restrict__ qkv,
                                              const unsigned short* __restrict__ vt,
                                              unsigned short* __restrict__ y){
  __shared__ unsigned short Ks[4][64 * 64];
  __shared__ unsigned short Vs[4][64 * 64];   // quad-interleaved Vt tile: [d][kv-perm]
  int tid = threadIdx.x, w = tid >> 6, ln = tid & 63, lq = ln & 15, lg = ln >> 4;
  int bh = blockIdx.y, b = bh >> 5, h = bh & 31, kvh = h >> 2;
  int q0 = blockIdx.x * 256;
  frag8 qF[2][2];
  #pragma unroll
  for (int s = 0; s < 2; ++s) {
    const unsigned short* qrow = qkv + (size_t)(b * Tn + q0 + w * 32 + 16 * s + lq) * NQKV + h * 64;
    qF[s][0] = *(const frag8*)(qrow + lg * 8);
    qF[s][1] = *(const frag8*)(qrow + 32 + lg * 8);
  }
  fx4 zero4 = (fx4){0.f, 0.f, 0.f, 0.f};
  asm volatile("" : "+v"(zero4));
  int n0 = tid;
  int r0 = n0 >> 3, c0 = (n0 & 7) ^ (r0 & 7);
  const unsigned short* kp0 = qkv + (size_t)b * Tn * NQKV + 2048 + kvh * 64 + (size_t)r0 * NQKV + c0 * 8;
  const unsigned short* vp0 = vt + ((size_t)(b * 8 + kvh) * 64 + r0) * Tn + c0 * 8;
  int koff0 = lq * 128 + (((lg)     ^ (lq & 7)) << 4);
  int koff1 = lq * 128 + (((lg + 4) ^ (lq & 7)) << 4);

#define STAGE(BUF) do {                                      \
    gld16(kp0, (char*)&Ks[BUF][0] + n0 * 16);                \
    gld16(vp0, (char*)&Vs[BUF][0] + n0 * 16);                \
    kp0 += 64 * NQKV; vp0 += 64;                             \
  } while (0)

#define PB(S, KK) ({ union { unsigned u[4]; frag8 f; } t_;                        \
    t_.u[0] = pu[S][2*(KK)][0]; t_.u[1] = pu[S][2*(KK)][1];                       \
    t_.u[2] = pu[S][2*(KK)+1][0]; t_.u[3] = pu[S][2*(KK)+1][1]; t_.f; })

#define PVSTEP(VF) do {                                                           \
    _Pragma("unroll")                                                             \
    for (int s = 0; s < 2; ++s)                                                   \
      _Pragma("unroll")                                                           \
      for (int df = 0; df < 4; ++df) {                                            \
        o[s][df] = MFMA(VF[df][0], PB(s, 0), o[s][df]);                           \
        o[s][df] = MFMA(VF[df][1], PB(s, 1), o[s][df]);                           \
      }                                                                           \
  } while (0)

#define TILE(BUF, VFCUR, VFPREV) do {                                             \
    const char* kb_ = (const char*)&Ks[BUF][0];                                   \
    const char* vb_ = (const char*)&Vs[BUF][0];                                   \
    frag8 kf[4][2];                                                               \
    _Pragma("unroll")                                                             \
    for (int mf = 0; mf < 4; ++mf) {                                              \
      kf[mf][0] = *(const frag8*)(kb_ + mf * 2048 + koff0);                       \
      kf[mf][1] = *(const frag8*)(kb_ + mf * 2048 + koff1);                       \
    }                                                                             \
    _Pragma("unroll")                                                             \
    for (int df = 0; df < 4; ++df) {                                              \
      VFCUR[df][0] = *(const frag8*)(vb_ + df * 2048 + koff0);                    \
      VFCUR[df][1] = *(const frag8*)(vb_ + df * 2048 + koff1);                    \
    }                                                                             \
    __builtin_amdgcn_s_setprio(1);                                                \
    PVSTEP(VFPREV);                                                               \
    fx4 sf[2][4];                                                                 \
    _Pragma("unroll")                                                             \
    for (int s = 0; s < 2; ++s)                                                   \
      _Pragma("unroll")                                                           \
      for (int mf = 0; mf < 4; ++mf) {                                            \
        sf[s][mf] = MFMA(kf[mf][0], qF[s][0], zero4);                             \
        sf[s][mf] = MFMA(kf[mf][1], qF[s][1], sf[s][mf]);                         \
      }                                                                           \
    __builtin_amdgcn_s_setprio(0);                                                \
    _Pragma("unroll")                                                             \
    for (int s = 0; s < 2; ++s) {                                                 \
      float ps = 0.f;                                                             \
      _Pragma("unroll")                                                           \
      for (int mf = 0; mf < 4; ++mf) {                                            \
        float p0 = sexp2(sf[s][mf][0]);                                           \
        float p1 = sexp2(sf[s][mf][1]);                                           \
        float p2 = sexp2(sf[s][mf][2]);                                           \
        float p3 = sexp2(sf[s][mf][3]);                                           \
        ps += (p0 + p1) + (p2 + p3);                                              \
        pu[s][mf][0] = cvtpk(p0, p1);                                             \
        pu[s][mf][1] = cvtpk(p2, p3);                                             \
      }                                                                           \
      lpart[s] += ps;                                                             \
    }                                                                             \
  } while (0)

  fx4 o[2][4];
  float lpart[2] = {0.f, 0.f};
  unsigned pu[2][4][2];
  frag8 vfA[4][2], vfB[4][2];
  #pragma unroll
  for (int s = 0; s < 2; ++s) {
    #pragma unroll
    for (int i = 0; i < 4; ++i) o[s][i] = (fx4){0.f, 0.f, 0.f, 0.f};
    #pragma unroll
    for (int mf = 0; mf < 4; ++mf) { pu[s][mf][0] = 0u; pu[s][mf][1] = 0u; }
  }
  #pragma unroll
  for (int df = 0; df < 4; ++df) {
    vfA[df][0] = (frag8){0,0,0,0,0,0,0,0};
    vfA[df][1] = (frag8){0,0,0,0,0,0,0,0};
  }

  STAGE(0); STAGE(1);
  __syncthreads();
  for (int kt = 0; kt < 32; kt += 4) {
    if (kt + 2 < 32) { STAGE(2); STAGE(3); }
    TILE(0, vfB, vfA);
    TILE(1, vfA, vfB);
    __syncthreads();
    if (kt + 4 < 32) { STAGE(0); STAGE(1); }
    TILE(2, vfB, vfA);
    TILE(3, vfA, vfB);
    __syncthreads();
  }
  __builtin_amdgcn_s_setprio(1);
  PVSTEP(vfA);
  __builtin_amdgcn_s_setprio(0);
#undef STAGE
#undef TILE
#undef PVSTEP
#undef PB

  #pragma unroll
  for (int s = 0; s < 2; ++s) {
    lpart[s] += __shfl_xor(lpart[s], 16);
    lpart[s] += __shfl_xor(lpart[s], 32);
    float inv = 1.0f / lpart[s];
    unsigned short* yp = y + (size_t)(b * Tn + q0 + w * 32 + 16 * s + lq) * Cn + h * 64;
    #pragma unroll
    for (int df = 0; df < 4; ++df) {
      unsigned lo = cvtpk(o[s][df][0] * inv, o[s][df][1] * inv);
      unsigned hi = cvtpk(o[s][df][2] * inv, o[s][df][3] * inv);
      *(uint2*)(yp + df * 16 + lg * 4) = make_uint2(lo, hi);
    }
  }
}

extern "C" void kernel_launch(void* const* d_in, const int* in_sizes, int n_in,
                              void* d_out, int out_size, void* d_ws, size_t ws_size,
                              hipStream_t stream){
  const float* x  = (const float*)d_in[0];
  const float* Wq = (const float*)d_in[1];
  const float* Wk = (const float*)d_in[2];
  const float* Wv = (const float*)d_in[3];
  const float* Wo = (const float*)d_in[4];
  char* ws = (char*)d_ws;
  size_t off = 0;
  unsigned short* xb    = (unsigned short*)(ws + off); off += (size_t)MR * KD * 2;
  unsigned short* wqkvt = (unsigned short*)(ws + off); off += (size_t)NQKV * KD * 2;
  unsigned short* wot   = (unsigned short*)(ws + off); off += (size_t)KD * KD * 2;
  unsigned short* qkv   = (unsigned short*)(ws + off); off += (size_t)MR * NQKV * 2;
  unsigned short* vtb   = (unsigned short*)(ws + off); off += (size_t)16 * 64 * Tn * 2;
  float2* cstab = (float2*)(ws + off); off += (size_t)Tn * 32 * 8;
  unsigned short* yb = xb;  // xb dead after GEMM1 -> reuse as attention output

  k_prep<<<4864, 256, 0, stream>>>(x, xb, Wq, Wk, Wv, wqkvt, Wo, wot, cstab);
  k_gemm<2><<<dim3(NQKV / 128, MR / 128), 256, 0, stream>>>(xb, wqkvt, qkv, MR, NQKV, KD, cstab, vtb);
  k_attn<<<dim3(Tn / 256, 64), 512, 0, stream>>>(qkv, vtb, yb);
  k_gemm<0><<<dim3(KD / 128, MR / 128), 256, 0, stream>>>(yb, wot, d_out, MR, KD, KD, nullptr, nullptr);
}

// Round 16
// 201.044 us; speedup vs baseline: 1.0706x; 1.0706x over previous
//
#include <hip/hip_runtime.h>
#include <stdint.h>

// ---- problem constants ----
#define Tn   2048
#define Cn   2048
#define Hn   32
#define KVHn 8
#define Dn   64
#define MR   4096   // B*T
#define NQKV 3072   // 2048 q | 512 k | 512 v
#define KD   2048

typedef __attribute__((ext_vector_type(4))) float fx4;
typedef __attribute__((ext_vector_type(8))) short frag8;

#define MFMA(a,b,c) __builtin_amdgcn_mfma_f32_16x16x32_bf16((a),(b),(c),0,0,0)

struct __align__(16) U16x8 { unsigned short s[8]; };

__device__ __forceinline__ unsigned short f2bf(float x){
  union { float f; unsigned u; } v; v.f = x;
  return (unsigned short)((v.u + 0x7FFFu + ((v.u >> 16) & 1u)) >> 16);
}
__device__ __forceinline__ float bf2f(unsigned short h){
  union { unsigned u; float f; } v; v.u = ((unsigned)h) << 16; return v.f;
}
// exp2 via compiler-known intrinsic (hazard-safe)
__device__ __forceinline__ float sexp2(float x){
#if __has_builtin(__builtin_amdgcn_exp2f)
  return __builtin_amdgcn_exp2f(x);
#else
  return exp2f(x);
#endif
}
__device__ __forceinline__ unsigned cvtpk(float a, float b){
  unsigned r; asm("v_cvt_pk_bf16_f32 %0, %1, %2" : "=v"(r) : "v"(a), "v"(b)); return r;
}

typedef const __attribute__((address_space(1))) void cas1_void;
typedef __attribute__((address_space(3))) void as3_void;
__device__ __forceinline__ void gld16(const void* g, void* l){
  __builtin_amdgcn_global_load_lds((cas1_void*)g, (as3_void*)l, 16, 0, 0);
}

// ---- merged prep: [0,2048) x->bf16 cvt | [2048,3584) transW qkv | [3584,4608) transW o | [4608,4864) rope table ----
__global__ __launch_bounds__(256) void k_prep(const float* __restrict__ x, unsigned short* __restrict__ xb,
                                              const float* __restrict__ Wq, const float* __restrict__ Wk,
                                              const float* __restrict__ Wv, unsigned short* __restrict__ wqkvt,
                                              const float* __restrict__ Wo, unsigned short* __restrict__ wot,
                                              float2* __restrict__ cs){
  __shared__ float tile[64][65];
  int blk = blockIdx.x, t = threadIdx.x;
  if (blk < 2048) {
    size_t blockbase = (size_t)blk * 4096;
    #pragma unroll
    for (int j = 0; j < 4; ++j) {
      size_t i = blockbase + j * 1024 + t * 4;
      float4 v = *(const float4*)(x + i);
      ushort4 o; o.x = f2bf(v.x); o.y = f2bf(v.y); o.z = f2bf(v.z); o.w = f2bf(v.w);
      *(ushort4*)(xb + i) = o;
    }
    return;
  }
  if (blk >= 4608) {
    int i = (blk - 4608) * 256 + t;
    int tp = i >> 5, d = i & 31;
    float inv = powf(10000.0f, -(float)d * (1.0f/32.0f));
    float fr = (float)tp * inv;
    cs[i] = make_float2(cosf(fr), sinf(fr));
    return;
  }
  const float* src; int col0, ld, n0, k0; unsigned short* outp;
  if (blk < 3584) {
    int bx = blk - 2048; n0 = (bx % 48) * 64; k0 = (bx / 48) * 64; outp = wqkvt;
    if (n0 < 2048)      { src = Wq; col0 = n0;        ld = 2048; }
    else if (n0 < 2560) { src = Wk; col0 = n0 - 2048; ld = 512;  }
    else                { src = Wv; col0 = n0 - 2560; ld = 512;  }
  } else {
    int bx = blk - 3584; n0 = (bx % 32) * 64; k0 = (bx / 32) * 64; outp = wot;
    src = Wo; col0 = n0; ld = 2048;
  }
  int r = t >> 2, cc = (t & 3) << 4;
  const float* p = src + (size_t)(k0 + r) * ld + col0 + cc;
  #pragma unroll
  for (int j = 0; j < 16; j += 4) {
    float4 v = *(const float4*)(p + j);
    tile[r][cc + j + 0] = v.x; tile[r][cc + j + 1] = v.y;
    tile[r][cc + j + 2] = v.z; tile[r][cc + j + 3] = v.w;
  }
  __syncthreads();
  int n = t >> 2, kc = (t & 3) << 4;
  unsigned short* q = outp + (size_t)(n0 + n) * 2048 + k0 + kc;
  U16x8 o0, o1;
  #pragma unroll
  for (int j = 0; j < 8; ++j) o0.s[j] = f2bf(tile[kc + j][n]);
  #pragma unroll
  for (int j = 0; j < 8; ++j) o1.s[j] = f2bf(tile[kc + 8 + j][n]);
  *(U16x8*)(q) = o0;
  *(U16x8*)(q + 8) = o1;
}

// ---- m97-style GEMM (no XCD swizzle: working set is L3-resident)
//      MODE 0: plain f32 C store (GEMM2)
//      MODE 2: fused epilogue (GEMM1): q/k blocks -> in-register rope -> bf16 qkv;
//              v blocks -> plain bf16 qkv store (coalesced; k_vt transposes)  ----
template<int MODE>
__global__ __launch_bounds__(256) void k_gemm(const unsigned short* __restrict__ A,
                                              const unsigned short* __restrict__ Bt,
                                              void* __restrict__ Cp,
                                              int M, int N, int K,
                                              const float2* __restrict__ cs){
  __shared__ unsigned short As[128 * 64];
  __shared__ unsigned short Bs[128 * 64];
  int tid = threadIdx.x;
  int m0 = blockIdx.y * 128, n0 = blockIdx.x * 128;
  int w = tid >> 6, ln = tid & 63, lr = ln & 15, lg = ln >> 4;
  int wm = (w >> 1) * 64, wn = (w & 1) * 64;
  fx4 acc[4][4];
  #pragma unroll
  for (int i = 0; i < 4; ++i)
    #pragma unroll
    for (int j = 0; j < 4; ++j) acc[i][j] = (fx4){0.f,0.f,0.f,0.f};
  int steps = K >> 6;
  for (int kt = 0; kt < steps; ++kt) {
    int kb = kt << 6;
    #pragma unroll
    for (int it = 0; it < 4; ++it) {
      int nch = it * 256 + tid;
      int r = nch >> 3, c = (nch & 7) ^ (r & 7);   // source-side swizzle, linear LDS dest
      gld16(A  + (size_t)(m0 + r) * K + kb + c * 8, (char*)As + nch * 16);
      gld16(Bt + (size_t)(n0 + r) * K + kb + c * 8, (char*)Bs + nch * 16);
    }
    __syncthreads();
    frag8 aF[4][2], bF[4][2];
    #pragma unroll
    for (int i = 0; i < 4; ++i) {
      int ra = wm + i * 16 + lr;
      int rb = wn + i * 16 + lr;
      #pragma unroll
      for (int kk = 0; kk < 2; ++kk) {
        aF[i][kk] = *(const frag8*)((const char*)As + ra * 128 + (((lg + 4*kk) ^ (ra & 7)) << 4));
        bF[i][kk] = *(const frag8*)((const char*)Bs + rb * 128 + (((lg + 4*kk) ^ (rb & 7)) << 4));
      }
    }
    #pragma unroll
    for (int kk = 0; kk < 2; ++kk)
      #pragma unroll
      for (int i = 0; i < 4; ++i)
        #pragma unroll
        for (int j = 0; j < 4; ++j)
          acc[i][j] = MFMA(aF[i][kk], bF[j][kk], acc[i][j]);
    __syncthreads();
  }
  if (MODE == 0) {
    #pragma unroll
    for (int i = 0; i < 4; ++i) {
      int row = m0 + wm + i * 16 + lg * 4;
      #pragma unroll
      for (int j = 0; j < 4; ++j) {
        int col = n0 + wn + j * 16 + lr;
        #pragma unroll
        for (int rr = 0; rr < 4; ++rr)
          ((float*)Cp)[(size_t)(row + rr) * N + col] = acc[i][j][rr];
      }
    }
  } else {
    int nb = n0 + wn;                       // 64-aligned -> one head per window
    unsigned short* outp = (unsigned short*)Cp;
    if (nb < 2560) {
      // ---- q/k block: rope in-register (fp32 accum), bf16 store to qkv ----
      float sc = (n0 < 2048) ? 0.180336880f : 1.0f;   // q: 0.125*log2(e)
      #pragma unroll
      for (int i = 0; i < 4; ++i) {
        int rowb = m0 + wm + i * 16 + lg * 4;
        #pragma unroll
        for (int jp = 0; jp < 2; ++jp) {
          int dA = jp * 16 + lr;            // d mod 32
          #pragma unroll
          for (int rr = 0; rr < 4; ++rr) {
            int row = rowb + rr;
            float2 cv = cs[((row & (Tn-1)) << 5) + dA];
            float a = acc[i][jp][rr], b = acc[i][jp + 2][rr];
            outp[(size_t)row * N + nb + dA]      = f2bf((a * cv.x - b * cv.y) * sc);
            outp[(size_t)row * N + nb + dA + 32] = f2bf((b * cv.x + a * cv.y) * sc);
          }
        }
      }
    } else {
      // ---- v block: plain bf16 store (coalesced); k_vt does the transpose ----
      #pragma unroll
      for (int i = 0; i < 4; ++i) {
        int row = m0 + wm + i * 16 + lg * 4;
        #pragma unroll
        for (int j = 0; j < 4; ++j) {
          int col = nb + j * 16 + lr;
          #pragma unroll
          for (int rr = 0; rr < 4; ++rr)
            outp[(size_t)(row + rr) * N + col] = f2bf(acc[i][j][rr]);
        }
      }
    }
  }
}

// ---- V pre-transpose WITH quad-interleave (slot-consistent with swapped-QK^T P regs) ----
__global__ __launch_bounds__(256) void k_vt(const unsigned short* __restrict__ qkv,
                                            unsigned short* __restrict__ vt){
  __shared__ unsigned short tl[64][66];   // [t][d]
  int head = blockIdx.y;
  int b = head >> 3, kvh = head & 7;
  int t0 = blockIdx.x * 64;
  int t = threadIdx.x;
  int r = t >> 2, cc = (t & 3) << 4;
  const unsigned short* p = qkv + (size_t)(b * Tn + t0 + r) * NQKV + 2560 + kvh * 64 + cc;
  U16x8 v0 = *(const U16x8*)(p);
  U16x8 v1 = *(const U16x8*)(p + 8);
  #pragma unroll
  for (int j = 0; j < 8; ++j) { tl[r][cc + j] = v0.s[j]; tl[r][cc + 8 + j] = v1.s[j]; }
  __syncthreads();
  int d = t >> 2, cpair = t & 3;
  unsigned short* q = vt + ((size_t)head * 64 + d) * Tn + t0;
  #pragma unroll
  for (int ci = 0; ci < 2; ++ci) {
    int c = cpair * 2 + ci;
    U16x8 oo;
    #pragma unroll
    for (int e = 0; e < 8; ++e)
      oo.s[e] = tl[32 * (c >> 2) + 16 * (e >> 2) + 4 * (c & 3) + (e & 3)][d];
    *(U16x8*)(q + c * 8) = oo;
  }
}

// ---- flash attention: QBLK=256 (8 waves x 32 q-rows), KVBLK=64, swapped QK^T,
//      fixed softmax origin (m=0, exp2 domain), P in registers, per-lane l,
//      cross-tile PV pipeline with double vf state, setprio on MFMA.
//      QUAD-BUFFERED LDS: one __syncthreads per TWO tiles (16 barriers total);
//      tiles kt+2,kt+3 staged in one burst while computing kt,kt+1. ----
__global__ __launch_bounds__(512) void k_attn(const unsigned short* __restrict__ qkv,
                                              const unsigned short* __restrict__ vt,
                                              unsigned short* __restrict__ y){
  __shared__ unsigned short Ks[4][64 * 64];
  __shared__ unsigned short Vs[4][64 * 64];   // quad-interleaved Vt tile: [d][kv-perm]
  int tid = threadIdx.x, w = tid >> 6, ln = tid & 63, lq = ln & 15, lg = ln >> 4;
  int bh = blockIdx.y, b = bh >> 5, h = bh & 31, kvh = h >> 2;
  int q0 = blockIdx.x * 256;
  frag8 qF[2][2];
  #pragma unroll
  for (int s = 0; s < 2; ++s) {
    const unsigned short* qrow = qkv + (size_t)(b * Tn + q0 + w * 32 + 16 * s + lq) * NQKV + h * 64;
    qF[s][0] = *(const frag8*)(qrow + lg * 8);
    qF[s][1] = *(const frag8*)(qrow + 32 + lg * 8);
  }
  fx4 zero4 = (fx4){0.f, 0.f, 0.f, 0.f};
  asm volatile("" : "+v"(zero4));
  int n0 = tid;
  int r0 = n0 >> 3, c0 = (n0 & 7) ^ (r0 & 7);
  const unsigned short* kp0 = qkv + (size_t)b * Tn * NQKV + 2048 + kvh * 64 + (size_t)r0 * NQKV + c0 * 8;
  const unsigned short* vp0 = vt + ((size_t)(b * 8 + kvh) * 64 + r0) * Tn + c0 * 8;
  int koff0 = lq * 128 + (((lg)     ^ (lq & 7)) << 4);
  int koff1 = lq * 128 + (((lg + 4) ^ (lq & 7)) << 4);

#define STAGE(BUF) do {                                      \
    gld16(kp0, (char*)&Ks[BUF][0] + n0 * 16);                \
    gld16(vp0, (char*)&Vs[BUF][0] + n0 * 16);                \
    kp0 += 64 * NQKV; vp0 += 64;                             \
  } while (0)

#define PB(S, KK) ({ union { unsigned u[4]; frag8 f; } t_;                        \
    t_.u[0] = pu[S][2*(KK)][0]; t_.u[1] = pu[S][2*(KK)][1];                       \
    t_.u[2] = pu[S][2*(KK)+1][0]; t_.u[3] = pu[S][2*(KK)+1][1]; t_.f; })

#define PVSTEP(VF) do {                                                           \
    _Pragma("unroll")                                                             \
    for (int s = 0; s < 2; ++s)                                                   \
      _Pragma("unroll")                                                           \
      for (int df = 0; df < 4; ++df) {                                            \
        o[s][df] = MFMA(VF[df][0], PB(s, 0), o[s][df]);                           \
        o[s][df] = MFMA(VF[df][1], PB(s, 1), o[s][df]);                           \
      }                                                                           \
  } while (0)

#define TILE(BUF, VFCUR, VFPREV) do {                                             \
    const char* kb_ = (const char*)&Ks[BUF][0];                                   \
    const char* vb_ = (const char*)&Vs[BUF][0];                                   \
    frag8 kf[4][2];                                                               \
    _Pragma("unroll")                                                             \
    for (int mf = 0; mf < 4; ++mf) {                                              \
      kf[mf][0] = *(const frag8*)(kb_ + mf * 2048 + koff0);                       \
      kf[mf][1] = *(const frag8*)(kb_ + mf * 2048 + koff1);                       \
    }                                                                             \
    _Pragma("unroll")                                                             \
    for (int df = 0; df < 4; ++df) {                                              \
      VFCUR[df][0] = *(const frag8*)(vb_ + df * 2048 + koff0);                    \
      VFCUR[df][1] = *(const frag8*)(vb_ + df * 2048 + koff1);                    \
    }                                                                             \
    __builtin_amdgcn_s_setprio(1);                                                \
    PVSTEP(VFPREV);                                                               \
    fx4 sf[2][4];                                                                 \
    _Pragma("unroll")                                                             \
    for (int s = 0; s < 2; ++s)                                                   \
      _Pragma("unroll")                                                           \
      for (int mf = 0; mf < 4; ++mf) {                                            \
        sf[s][mf] = MFMA(kf[mf][0], qF[s][0], zero4);                             \
        sf[s][mf] = MFMA(kf[mf][1], qF[s][1], sf[s][mf]);                         \
      }                                                                           \
    __builtin_amdgcn_s_setprio(0);                                                \
    _Pragma("unroll")                                                             \
    for (int s = 0; s < 2; ++s) {                                                 \
      float ps = 0.f;                                                             \
      _Pragma("unroll")                                                           \
      for (int mf = 0; mf < 4; ++mf) {                                            \
        float p0 = sexp2(sf[s][mf][0]);                                           \
        float p1 = sexp2(sf[s][mf][1]);                                           \
        float p2 = sexp2(sf[s][mf][2]);                                           \
        float p3 = sexp2(sf[s][mf][3]);                                           \
        ps += (p0 + p1) + (p2 + p3);                                              \
        pu[s][mf][0] = cvtpk(p0, p1);                                             \
        pu[s][mf][1] = cvtpk(p2, p3);                                             \
      }                                                                           \
      lpart[s] += ps;                                                             \
    }                                                                             \
  } while (0)

  fx4 o[2][4];
  float lpart[2] = {0.f, 0.f};
  unsigned pu[2][4][2];
  frag8 vfA[4][2], vfB[4][2];
  #pragma unroll
  for (int s = 0; s < 2; ++s) {
    #pragma unroll
    for (int i = 0; i < 4; ++i) o[s][i] = (fx4){0.f, 0.f, 0.f, 0.f};
    #pragma unroll
    for (int mf = 0; mf < 4; ++mf) { pu[s][mf][0] = 0u; pu[s][mf][1] = 0u; }
  }
  #pragma unroll
  for (int df = 0; df < 4; ++df) {
    vfA[df][0] = (frag8){0,0,0,0,0,0,0,0};
    vfA[df][1] = (frag8){0,0,0,0,0,0,0,0};
  }

  STAGE(0); STAGE(1);
  __syncthreads();
  for (int kt = 0; kt < 32; kt += 4) {
    if (kt + 2 < 32) { STAGE(2); STAGE(3); }
    TILE(0, vfB, vfA);
    TILE(1, vfA, vfB);
    __syncthreads();
    if (kt + 4 < 32) { STAGE(0); STAGE(1); }
    TILE(2, vfB, vfA);
    TILE(3, vfA, vfB);
    __syncthreads();
  }
  __builtin_amdgcn_s_setprio(1);
  PVSTEP(vfA);
  __builtin_amdgcn_s_setprio(0);
#undef STAGE
#undef TILE
#undef PVSTEP
#undef PB

  #pragma unroll
  for (int s = 0; s < 2; ++s) {
    lpart[s] += __shfl_xor(lpart[s], 16);
    lpart[s] += __shfl_xor(lpart[s], 32);
    float inv = 1.0f / lpart[s];
    unsigned short* yp = y + (size_t)(b * Tn + q0 + w * 32 + 16 * s + lq) * Cn + h * 64;
    #pragma unroll
    for (int df = 0; df < 4; ++df) {
      unsigned lo = cvtpk(o[s][df][0] * inv, o[s][df][1] * inv);
      unsigned hi = cvtpk(o[s][df][2] * inv, o[s][df][3] * inv);
      *(uint2*)(yp + df * 16 + lg * 4) = make_uint2(lo, hi);
    }
  }
}

extern "C" void kernel_launch(void* const* d_in, const int* in_sizes, int n_in,
                              void* d_out, int out_size, void* d_ws, size_t ws_size,
                              hipStream_t stream){
  const float* x  = (const float*)d_in[0];
  const float* Wq = (const float*)d_in[1];
  const float* Wk = (const float*)d_in[2];
  const float* Wv = (const float*)d_in[3];
  const float* Wo = (const float*)d_in[4];
  char* ws = (char*)d_ws;
  size_t off = 0;
  unsigned short* xb    = (unsigned short*)(ws + off); off += (size_t)MR * KD * 2;
  unsigned short* wqkvt = (unsigned short*)(ws + off); off += (size_t)NQKV * KD * 2;
  unsigned short* wot   = (unsigned short*)(ws + off); off += (size_t)KD * KD * 2;
  unsigned short* qkv   = (unsigned short*)(ws + off); off += (size_t)MR * NQKV * 2;
  unsigned short* vtb   = (unsigned short*)(ws + off); off += (size_t)16 * 64 * Tn * 2;
  float2* cstab = (float2*)(ws + off); off += (size_t)Tn * 32 * 8;
  unsigned short* yb = xb;  // xb dead after GEMM1 -> reuse as attention output

  k_prep<<<4864, 256, 0, stream>>>(x, xb, Wq, Wk, Wv, wqkvt, Wo, wot, cstab);
  k_gemm<2><<<dim3(NQKV / 128, MR / 128), 256, 0, stream>>>(xb, wqkvt, qkv, MR, NQKV, KD, cstab);
  k_vt<<<dim3(Tn / 64, 16), 256, 0, stream>>>(qkv, vtb);
  k_attn<<<dim3(Tn / 256, 64), 512, 0, stream>>>(qkv, vtb, yb);
  k_gemm<0><<<dim3(KD / 128, MR / 128), 256, 0, stream>>>(yb, wot, d_out, MR, KD, KD, nullptr);
}